// Round 11
// baseline (1240.501 us; speedup 1.0000x reference)
//
#include <hip/hip_runtime.h>
#include <hip/hip_bf16.h>
#include <math.h>

// Problem constants (MambaStack reference)
#define DEPTH   2
#define DM      768      // d_model
#define DS      64       // d_state
#define DC      4        // d_conv
#define DI      1536     // d_inner
#define DTR     48       // dt_rank
#define BATCH   4
#define SEQ     2048
#define MROWS   (BATCH*SEQ)          // 8192
#define XDC     (DTR + 2*DS)         // 176 (xdbl cols)
#define NC      8                    // scan chunks
#define TCH     (SEQ/NC)             // 256 timesteps per chunk
#define LOG2E   1.44269504088896f

typedef __attribute__((ext_vector_type(8))) short bf16x8;
typedef __attribute__((ext_vector_type(4))) float f32x4;
typedef __attribute__((ext_vector_type(2))) float f32x2;
typedef __attribute__((ext_vector_type(2))) unsigned int uint2v;
typedef unsigned short ushort_t;
#define GAS __attribute__((address_space(1)))
#define LAS __attribute__((address_space(3)))

__device__ __forceinline__ float silu_fast(float x) {
    return x / (1.f + __expf(-x));
}
__device__ __forceinline__ float softplus_acc(float x) {
    return x > 20.f ? x : log1pf(expf(x));
}

// RNE fp32 -> bf16.
__device__ __forceinline__ ushort_t bf16_hi(float f) {
    unsigned u = __float_as_uint(f);
    unsigned hr = u + 0x7FFF + ((u >> 16) & 1);
    return (ushort_t)(hr >> 16);
}
__device__ __forceinline__ float bf16_f32(ushort_t u) {
    return __uint_as_float((unsigned)u << 16);
}

// ---------- VALU-pipe cross-lane reduction helpers (float2, no LDS) ----------
__device__ __forceinline__ f32x2 merge_x32_2(f32x2 a, f32x2 b) {
#if __has_builtin(__builtin_amdgcn_permlane32_swap)
    const uint2v rx = __builtin_amdgcn_permlane32_swap(
        __float_as_uint(a.x), __float_as_uint(b.x), false, false);
    const uint2v ry = __builtin_amdgcn_permlane32_swap(
        __float_as_uint(a.y), __float_as_uint(b.y), false, false);
    const f32x2 s0 = {__uint_as_float(rx[0]), __uint_as_float(ry[0])};
    const f32x2 s1 = {__uint_as_float(rx[1]), __uint_as_float(ry[1])};
    return s0 + s1;
#else
    const f32x2 sa = {a.x + __shfl_xor(a.x, 32, 64), a.y + __shfl_xor(a.y, 32, 64)};
    const f32x2 sb = {b.x + __shfl_xor(b.x, 32, 64), b.y + __shfl_xor(b.y, 32, 64)};
    return (threadIdx.x & 32) ? sb : sa;
#endif
}

__device__ __forceinline__ f32x2 merge_x16_2(f32x2 a, f32x2 b) {
#if __has_builtin(__builtin_amdgcn_permlane16_swap)
    const uint2v rx = __builtin_amdgcn_permlane16_swap(
        __float_as_uint(a.x), __float_as_uint(b.x), false, false);
    const uint2v ry = __builtin_amdgcn_permlane16_swap(
        __float_as_uint(a.y), __float_as_uint(b.y), false, false);
    const f32x2 s0 = {__uint_as_float(rx[0]), __uint_as_float(ry[0])};
    const f32x2 s1 = {__uint_as_float(rx[1]), __uint_as_float(ry[1])};
    return s0 + s1;
#else
    const f32x2 sa = {a.x + __shfl_xor(a.x, 16, 64), a.y + __shfl_xor(a.y, 16, 64)};
    const f32x2 sb = {b.x + __shfl_xor(b.x, 16, 64), b.y + __shfl_xor(b.y, 16, 64)};
    return (threadIdx.x & 16) ? sb : sa;
#endif
}

template <int CTRL>
__device__ __forceinline__ f32x2 dpp_add2(f32x2 x) {
    const int tx = __builtin_amdgcn_update_dpp(
        0, __float_as_int(x.x), CTRL, 0xF, 0xF, true);
    const int ty = __builtin_amdgcn_update_dpp(
        0, __float_as_int(x.y), CTRL, 0xF, 0xF, true);
    const f32x2 t = {__int_as_float(tx), __int_as_float(ty)};
    return x + t;
}
__device__ __forceinline__ f32x2 rowsum16_2(f32x2 x) {
    x = dpp_add2<0x128>(x);   // row_ror:8
    x = dpp_add2<0x124>(x);   // row_ror:4
    x = dpp_add2<0x122>(x);   // row_ror:2
    x = dpp_add2<0x121>(x);   // row_ror:1
    return x;
}

// Contiguous fp32 array -> single bf16 plane.  n multiple of 1024.
__global__ __launch_bounds__(256) void quant_bf16(
    const float* __restrict__ in, ushort_t* __restrict__ hi)
{
    const size_t i = ((size_t)blockIdx.x * 256 + threadIdx.x) * 4;
    const float4 v = *(const float4*)(in + i);
    ushort4 h;
    h.x = bf16_hi(v.x); h.y = bf16_hi(v.y);
    h.z = bf16_hi(v.z); h.w = bf16_hi(v.w);
    *(ushort4*)(hi + i) = h;
}

// ---------------- single-plane bf16 MFMA GEMM ----------------
// C[M,N] = A @ W^T, both single bf16 planes.
// 128x128 tile, BK=32, 4 waves, 1 MFMA per fragment, 2 LDS buffers,
// 16 staging loads per K-step (wave w stages ldid = 4w..4w+3).
// mode 0: fp32 C[row*N+col], col<N guard.
// mode 1: bf16 plane into Chi (row stride N)  [in-proj xzh, layer-0 out]
// mode 2: x_proj fused: cols [DTR,DTR+128) -> lane-interleaved bc4 quads,
//         cols <DTR -> fp32 C (stride N), cols >=176 dropped.
// XCD-aware bijective block remap (gridDim.y % 8 == 0 at all call sites).
__global__ __launch_bounds__(256, 2) void gemm_mfma(
    const ushort_t* __restrict__ A, const ushort_t* __restrict__ W,
    float* __restrict__ C, int N, int K, int ldA, int ldW,
    ushort_t* __restrict__ Chi, float4* __restrict__ bc4out, int mode)
{
    __shared__ ushort_t lds[2][128 * 32];
    const int tid  = threadIdx.x;
    const int wave = tid >> 6, lane = tid & 63;

    int bx = blockIdx.x, by = blockIdx.y;
    {   // T1 bijective XCD swizzle
        const int X   = gridDim.x;
        const int fid = by * X + bx;
        const int xcd = fid & 7;
        const int j   = fid >> 3;
        const int jX  = j / X;
        by = xcd * (gridDim.y >> 3) + jX;
        bx = j - jX * X;
    }
    const int bm0 = by * 128, bn0 = bx * 128;
    const int wm = (wave >> 1) * 64, wn = (wave & 1) * 64;

    const int srow = lane >> 2;           // 0..15
    const int skq  = (lane & 3) * 8;      // k offset in elements

    f32x4 acc[4][4];
#pragma unroll
    for (int i = 0; i < 4; i++)
#pragma unroll
        for (int j = 0; j < 4; j++) acc[i][j] = (f32x4){0.f, 0.f, 0.f, 0.f};

    const int lm  = lane & 15;
    const int kg8 = (lane >> 4) * 8;

    for (int k0 = 0; k0 < K; k0 += 32) {
#pragma unroll
        for (int j = 0; j < 4; j++) {
            const int ldid = wave * 4 + j;          // 0..15
            const int buf  = ldid >> 3;             // 0:A 1:W
            const int slot = ldid & 7;
            const ushort_t* gsrc = buf ? W : A;
            const int ldg = buf ? ldW : ldA;
            const int rb  = buf ? bn0 : bm0;
            const ushort_t* ga = gsrc + (size_t)(rb + slot * 16 + srow) * ldg + k0 + skq;
            __builtin_amdgcn_global_load_lds(
                (const GAS unsigned*)ga, (LAS unsigned*)&lds[buf][slot * 512], 16, 0, 0);
        }
        __syncthreads();

        bf16x8 ah[4], bh[4];
#pragma unroll
        for (int i = 0; i < 4; i++) {
            const int ar = (wm + i * 16 + lm) * 32 + kg8;
            ah[i] = *(const bf16x8*)&lds[0][ar];
            const int br = (wn + i * 16 + lm) * 32 + kg8;
            bh[i] = *(const bf16x8*)&lds[1][br];
        }
#pragma unroll
        for (int mi = 0; mi < 4; mi++)
#pragma unroll
            for (int ni = 0; ni < 4; ni++)
                acc[mi][ni] = __builtin_amdgcn_mfma_f32_16x16x32_bf16(
                    ah[mi], bh[ni], acc[mi][ni], 0, 0, 0);
        __syncthreads();
    }

#pragma unroll
    for (int mi = 0; mi < 4; mi++)
#pragma unroll
        for (int ni = 0; ni < 4; ni++) {
            const int rowb = bm0 + wm + mi * 16 + (lane >> 4) * 4;  // mult of 4
            const int colg = bn0 + wn + ni * 16 + lm;
            if (mode == 1) {
#pragma unroll
                for (int r = 0; r < 4; r++)
                    Chi[(size_t)(rowb + r) * N + colg] = bf16_hi(acc[mi][ni][r]);
            } else if (mode == 2) {
                if (colg >= DTR && colg < DTR + 2 * DS) {
                    const f32x4 a = acc[mi][ni];
                    bc4out[(size_t)(rowb >> 2) * 128 + (colg - DTR)] =
                        make_float4(a[0], a[1], a[2], a[3]);
                } else if (colg < DTR) {
#pragma unroll
                    for (int r = 0; r < 4; r++)
                        C[(size_t)(rowb + r) * N + colg] = acc[mi][ni][r];
                }
            } else {
#pragma unroll
                for (int r = 0; r < 4; r++)
                    if (colg < N)
                        C[(size_t)(rowb + r) * N + colg] = acc[mi][ni][r];
            }
        }
}

// dt GEMM, transposed output: dtT[(b*DI+d)*SEQ + t] =
//   softplus(sum_k Wdt[d][k] * xdbl[b*SEQ+t][k] + bias[d]).
__global__ __launch_bounds__(256, 2) void gemm_dt_T(
    const float* __restrict__ Wdt, const float* __restrict__ xdbl,
    const float* __restrict__ bias, float* __restrict__ dtT)
{
    __shared__ float As[8][132];
    __shared__ float Bs[8][132];
    const int tid = threadIdx.x;
    const int bd0 = blockIdx.y * 128;   // d tile
    const int bt0 = blockIdx.x * 128;   // t tile
    const int b   = blockIdx.z;
    const int tx = tid & 15;            // t group
    const int ty = tid >> 4;            // d group
    const int lrow = tid >> 1;
    const int lk4  = (tid & 1) * 4;

    float acc[8][8];
#pragma unroll
    for (int i = 0; i < 8; i++)
#pragma unroll
        for (int j = 0; j < 8; j++) acc[i][j] = 0.f;

    for (int k0 = 0; k0 < DTR; k0 += 8) {
        const float4 av = *(const float4*)(Wdt + (size_t)(bd0 + lrow) * DTR + k0 + lk4);
        const float4 wv = *(const float4*)(xdbl + ((size_t)b * SEQ + bt0 + lrow) * XDC + k0 + lk4);
        __syncthreads();
        As[lk4 + 0][lrow] = av.x; As[lk4 + 1][lrow] = av.y;
        As[lk4 + 2][lrow] = av.z; As[lk4 + 3][lrow] = av.w;
        Bs[lk4 + 0][lrow] = wv.x; Bs[lk4 + 1][lrow] = wv.y;
        Bs[lk4 + 2][lrow] = wv.z; Bs[lk4 + 3][lrow] = wv.w;
        __syncthreads();
#pragma unroll
        for (int kk = 0; kk < 8; kk++) {
            const float4 a0 = *(const float4*)&As[kk][ty * 8];
            const float4 a1 = *(const float4*)&As[kk][ty * 8 + 4];
            const float4 b0 = *(const float4*)&Bs[kk][tx * 8];
            const float4 b1 = *(const float4*)&Bs[kk][tx * 8 + 4];
            const float ar[8] = {a0.x, a0.y, a0.z, a0.w, a1.x, a1.y, a1.z, a1.w};
            const float br[8] = {b0.x, b0.y, b0.z, b0.w, b1.x, b1.y, b1.z, b1.w};
#pragma unroll
            for (int i = 0; i < 8; i++)
#pragma unroll
                for (int j = 0; j < 8; j++)
                    acc[i][j] = fmaf(ar[i], br[j], acc[i][j]);
        }
    }

#pragma unroll
    for (int i = 0; i < 8; i++) {
        const int d = bd0 + ty * 8 + i;
        const float bb = bias[d];
#pragma unroll
        for (int j4 = 0; j4 < 8; j4 += 4) {
            float4 v = make_float4(acc[i][j4], acc[i][j4 + 1], acc[i][j4 + 2], acc[i][j4 + 3]);
            v.x = softplus_acc(v.x + bb);
            v.y = softplus_acc(v.y + bb);
            v.z = softplus_acc(v.z + bb);
            v.w = softplus_acc(v.w + bb);
            *(float4*)(dtT + ((size_t)b * DI + d) * SEQ + bt0 + tx * 8 + j4) = v;
        }
    }
}

// Depthwise causal conv (K=4) + SiLU -> uT [b][d][t] fp32 AND row-major
// bf16 plane.  Input xzh is the bf16 in-proj output plane.
__global__ __launch_bounds__(256) void conv_silu_T2(
    const ushort_t* __restrict__ xzh, const float* __restrict__ cw,
    const float* __restrict__ cb, float* __restrict__ uT,
    ushort_t* __restrict__ uh)
{
    __shared__ float tin[67][65];
    __shared__ float ttr[64][65];
    const int tid = threadIdx.x;
    const int d0 = blockIdx.x * 64, t0 = blockIdx.y * 64, b = blockIdx.z;
    const int cl = tid & 63, q = tid >> 6;

    for (int r = q; r < 67; r += 4) {
        const int t = t0 - 3 + r;
        float v = 0.f;
        if (t >= 0) v = bf16_f32(xzh[((size_t)b * SEQ + t) * (2 * DI) + d0 + cl]);
        tin[r][cl] = v;
    }
    __syncthreads();

    const float4 w = ((const float4*)cw)[d0 + cl];
    const float bb = cb[d0 + cl];
#pragma unroll
    for (int i = 0; i < 16; i++) {
        const int t = q * 16 + i;
        float a = bb;
        a = fmaf(tin[t + 0][cl], w.x, a);
        a = fmaf(tin[t + 1][cl], w.y, a);
        a = fmaf(tin[t + 2][cl], w.z, a);
        a = fmaf(tin[t + 3][cl], w.w, a);
        a = silu_fast(a);
        ttr[cl][t] = a;
        const size_t row = (size_t)b * SEQ + t0 + t;
        uh[row * DI + d0 + cl] = bf16_hi(a);   // coalesced in d
    }
    __syncthreads();
#pragma unroll
    for (int i = 0; i < 16; i++) {
        const int d = q * 16 + i;
        uT[((size_t)b * DI + d0 + d) * SEQ + t0 + cl] = ttr[d][cl];  // coalesced in t
    }
}

// ---------------- Chunked selective scan ----------------
// s output now has its own fp32 buffer sbuf[(b*DI+d)*SEQ + t] (no aliasing map).

// Channel-paired truncated-backward chunk-end state (f32x2, shared B):
//   hend = sum_t exp2(An * R_t) * dt_t*u_t*B_t,   R_t = suffix-sum of dt.
// Early exit when BOTH channels' remaining weights underflow 2^-30.
#define TAIL_STEP(E, G)                                                \
    {                                                                  \
        const f32x2 dte = {dt0[G].E, dt1[G].E};                        \
        const f32x2 ue  = {u0v[G].E, u1v[G].E};                        \
        const f32x2 w2  = An2 * r2;                                    \
        const f32x2 ee  = {__builtin_amdgcn_exp2f(w2.x),               \
                           __builtin_amdgcn_exp2f(w2.y)};              \
        h2 = h2 + ee * ((dte * ue) * B4[G].E);                         \
        r2 = r2 + dte;                                                 \
    }

__global__ __launch_bounds__(256, 2) void scan_tail(
    const float* __restrict__ dtT, const float* __restrict__ uT,
    const float4* __restrict__ bc4, const float* __restrict__ A_log,
    float* __restrict__ hend)
{
    const int wid  = __builtin_amdgcn_readfirstlane(
                        (int)((blockIdx.x * 256 + threadIdx.x) >> 6));
    const int lane = threadIdx.x & 63;
    const int c   = wid & (NC - 1);
    const int bdq = wid >> 3;
    const int bd0 = bdq * 2;
    const int b   = bd0 / DI;
    const int d0  = bd0 - b * DI;

    const f32x2 An2 = {-expf(A_log[(size_t)d0 * DS + lane]) * LOG2E,
                       -expf(A_log[(size_t)(d0 + 1) * DS + lane]) * LOG2E};
    const float* dtp0 = dtT + (size_t)bd0 * SEQ + c * TCH;
    const float* dtp1 = dtp0 + SEQ;
    const float* up0  = uT  + (size_t)bd0 * SEQ + c * TCH;
    const float* up1  = up0 + SEQ;
    const float4* Bp = bc4 + ((size_t)b * (SEQ / 4) + c * (TCH / 4)) * 128 + lane;

    f32x2 h2 = {0.f, 0.f}, r2 = {0.f, 0.f};
    for (int tb = TCH - 16; tb >= 0; tb -= 16) {
        float4 dt0[4], dt1[4], u0v[4], u1v[4], B4[4];
#pragma unroll
        for (int g = 0; g < 4; g++) {
            dt0[g] = *(const float4*)(dtp0 + tb + 4 * g);
            dt1[g] = *(const float4*)(dtp1 + tb + 4 * g);
            u0v[g] = *(const float4*)(up0 + tb + 4 * g);
            u1v[g] = *(const float4*)(up1 + tb + 4 * g);
            B4[g]  = Bp[(size_t)(tb / 4 + g) * 128];
        }
#pragma unroll
        for (int g = 3; g >= 0; g--) {
            TAIL_STEP(w, g)
            TAIL_STEP(z, g)
            TAIL_STEP(y, g)
            TAIL_STEP(x, g)
        }
        if (__all((An2.x * r2.x < -30.f) && (An2.y * r2.y < -30.f))) break;
    }
    hend[((size_t)bd0 * NC + c) * DS + lane]       = h2.x;
    hend[((size_t)(bd0 + 1) * NC + c) * DS + lane] = h2.y;
}

// Cross-chunk combine (computes per-chunk dt sums internally).
__global__ __launch_bounds__(256) void scan_phase2(
    const float* __restrict__ dtT, const float* __restrict__ A_log,
    const float* __restrict__ hend, float* __restrict__ h0out)
{
    const int bd   = (blockIdx.x * 256 + threadIdx.x) >> 6;
    const int lane = threadIdx.x & 63;
    const int d    = bd % DI;

    const float* dtp = dtT + (size_t)bd * SEQ + lane * 32;
    float s = 0.f;
#pragma unroll
    for (int g = 0; g < 8; g++) {
        const float4 v = *(const float4*)(dtp + 4 * g);
        s += (v.x + v.y) + (v.z + v.w);
    }
    s += __shfl_xor(s, 1, 64);
    s += __shfl_xor(s, 2, 64);
    s += __shfl_xor(s, 4, 64);   // lanes 8c..8c+7 all hold chunk-c sum

    const float An = -expf(A_log[d * DS + lane]) * LOG2E;
    float h = 0.f;
#pragma unroll
    for (int c = 0; c < NC; c++) {
        const float sdt = __shfl(s, 8 * c, 64);
        const size_t off = ((size_t)bd * NC + c) * DS + lane;
        h0out[off] = h;
        h = fmaf(__builtin_amdgcn_exp2f(An * sdt), h, hend[off]);
    }
}

// Channel-paired packed-fp32 full scan (R9-verified structure; s output to
// the dedicated sbuf, plain [bd*SEQ + t] indexing).

#define LOAD6(D0, D1, U0, U1, BB_, CC_, TB)                            \
    _Pragma("unroll")                                                  \
    for (int g = 0; g < 4; g++) {                                      \
        D0[g]  = *(const float4*)(dtp0 + (TB) + 4 * g);                \
        D1[g]  = *(const float4*)(dtp1 + (TB) + 4 * g);                \
        U0[g]  = *(const float4*)(up0 + (TB) + 4 * g);                 \
        U1[g]  = *(const float4*)(up1 + (TB) + 4 * g);                 \
        BB_[g] = Bp[(size_t)((TB) / 4 + g) * 128];                     \
        CC_[g] = Cp[(size_t)((TB) / 4 + g) * 128];                     \
    }

#define P3_STEP(E, G, D0, D1, U0, U1, BB_, CC_, LF)                    \
    {                                                                  \
        const f32x2 dte = {D0[G].E, D1[G].E};                          \
        const f32x2 ue  = {U0[G].E, U1[G].E};                          \
        f32x2 w2 = dte * An2;                                          \
        const f32x2 ee = {__builtin_amdgcn_exp2f(w2.x),                \
                          __builtin_amdgcn_exp2f(w2.y)};               \
        const f32x2 p2 = (dte * ue) * BB_[G].E;                        \
        h2 = ee * h2 + p2;                                             \
        LF = h2 * CC_[G].E;                                            \
    }

#define P3_BLOCK(D0, D1, U0, U1, BB_, CC_, TBASE)                      \
    {                                                                  \
        f32x2 m[8];                                                    \
        _Pragma("unroll")                                              \
        for (int g = 0; g < 4; g++) {                                  \
            f32x2 lf0, lf1, lf2, lf3;                                  \
            P3_STEP(x, g, D0, D1, U0, U1, BB_, CC_, lf0)               \
            P3_STEP(y, g, D0, D1, U0, U1, BB_, CC_, lf1)               \
            P3_STEP(z, g, D0, D1, U0, U1, BB_, CC_, lf2)               \
            P3_STEP(w, g, D0, D1, U0, U1, BB_, CC_, lf3)               \
            m[2 * g]     = merge_x32_2(lf0, lf1);                      \
            m[2 * g + 1] = merge_x32_2(lf2, lf3);                      \
        }                                                              \
        const f32x2 q0 = rowsum16_2(merge_x16_2(m[0], m[1]));          \
        const f32x2 q1 = rowsum16_2(merge_x16_2(m[2], m[3]));          \
        const f32x2 q2 = rowsum16_2(merge_x16_2(m[4], m[5]));          \
        const f32x2 q3 = rowsum16_2(merge_x16_2(m[6], m[7]));          \
        const f32x2 v = (lane & 2) ? ((lane & 1) ? q3 : q2)            \
                                   : ((lane & 1) ? q1 : q0);           \
        if ((lane & 15) < 4) {                                         \
            sp0[(TBASE) + wtt] = v.x;                                  \
            sp1[(TBASE) + wtt] = v.y;                                  \
        }                                                              \
    }

__global__ __launch_bounds__(256, 2) void scan_phase3(
    const float* __restrict__ dtT, const float* __restrict__ uT,
    const float4* __restrict__ bc4, const float* __restrict__ A_log,
    const float* __restrict__ hin, float* __restrict__ sX)
{
    const int tid  = threadIdx.x;
    const int wid  = __builtin_amdgcn_readfirstlane(
                        (int)((blockIdx.x * 256 + tid) >> 6));
    const int lane = tid & 63;
    const int c   = wid & (NC - 1);
    const int bdq = wid >> 3;
    const int bd0 = bdq * 2;             // channel pair (bd0, bd0+1), same b
    const int b   = bd0 / DI;
    const int d0  = bd0 - b * DI;

    const f32x2 An2 = {-expf(A_log[(size_t)d0 * DS + lane]) * LOG2E,
                       -expf(A_log[(size_t)(d0 + 1) * DS + lane]) * LOG2E};

    const float* dtp0 = dtT + (size_t)bd0 * SEQ + c * TCH;
    const float* dtp1 = dtp0 + SEQ;
    const float* up0  = uT  + (size_t)bd0 * SEQ + c * TCH;
    const float* up1  = up0 + SEQ;
    const float4* Bp = bc4 + ((size_t)b * (SEQ / 4) + c * (TCH / 4)) * 128 + lane;
    const float4* Cp = Bp + 64;

    float* sp0 = sX + (size_t)bd0 * SEQ + c * TCH;
    float* sp1 = sp0 + SEQ;

    // writer mapping for the fold-tree reduce: perm[r] = [0,2,1,3]
    const int wr  = lane >> 4;
    const int wtt = 4 * (lane & 3) + (((wr & 1) << 1) | (wr >> 1));

    f32x2 h2 = {hin[((size_t)bd0 * NC + c) * DS + lane],
                hin[((size_t)(bd0 + 1) * NC + c) * DS + lane]};

    float4 dA0[4], dA1[4], uA0[4], uA1[4], BA4[4], CA4[4];
    float4 dB0[4], dB1[4], uB0[4], uB1[4], BB4[4], CB4[4];
    LOAD6(dA0, dA1, uA0, uA1, BA4, CA4, 0);

    for (int tb = 0; tb < TCH; tb += 32) {
        LOAD6(dB0, dB1, uB0, uB1, BB4, CB4, tb + 16);
        P3_BLOCK(dA0, dA1, uA0, uA1, BA4, CA4, tb);
        LOAD6(dA0, dA1, uA0, uA1, BA4, CA4, tb + 32);  // final iter overreads (safe)
        P3_BLOCK(dB0, dB1, uB0, uB1, BB4, CB4, tb + 16);
    }
}

// Fused gate + transpose + bf16 quantize:
//   y = (s + D*u) * silu(z); s from sbuf fp32, z from xzh bf16 plane.
__global__ __launch_bounds__(256) void gate_split_T(
    const ushort_t* __restrict__ xzh, const float* __restrict__ sbuf,
    const float* __restrict__ uT, const float* __restrict__ Dskip,
    ushort_t* __restrict__ yh)
{
    __shared__ float zt[64][65];   // [t][d]
    __shared__ float yt[64][65];   // [d][t]
    const int tid = threadIdx.x;
    const int d0 = blockIdx.x * 64, t0 = blockIdx.y * 64, b = blockIdx.z;
    const int cl = tid & 63, q = tid >> 6;
#pragma unroll
    for (int i = 0; i < 16; i++) {
        const int r = q * 16 + i;
        zt[r][cl] = bf16_f32(xzh[((size_t)b * SEQ + t0 + r) * (2 * DI) + DI + d0 + cl]);
    }
    __syncthreads();
#pragma unroll
    for (int i = 0; i < 16; i++) {
        const int dd = q * 16 + i;
        const size_t Lrow = ((size_t)b * DI + d0 + dd) * SEQ + t0;
        const float s = sbuf[Lrow + cl];
        const float u = uT[Lrow + cl];
        const float Dd = Dskip[d0 + dd];   // wave-uniform
        yt[dd][cl] = (s + Dd * u) * silu_fast(zt[cl][dd]);
    }
    __syncthreads();
#pragma unroll
    for (int i = 0; i < 16; i++) {
        const int t = q * 16 + i;
        const size_t row = (size_t)b * SEQ + t0 + t;
        yh[row * DI + d0 + cl] = bf16_hi(yt[cl][t]);   // coalesced in d
    }
}

extern "C" void kernel_launch(void* const* d_in, const int* in_sizes, int n_in,
                              void* d_out, int out_size, void* d_ws, size_t ws_size,
                              hipStream_t stream) {
    (void)in_sizes; (void)n_in; (void)out_size; (void)ws_size;
    const float* x    = (const float*)d_in[0];
    const float* Wi   = (const float*)d_in[1];
    const float* cw   = (const float*)d_in[2];
    const float* cb   = (const float*)d_in[3];
    const float* Wx   = (const float*)d_in[4];
    const float* Wdt  = (const float*)d_in[5];
    const float* bdt  = (const float*)d_in[6];
    const float* Alog = (const float*)d_in[7];
    const float* Dsk  = (const float*)d_in[8];
    const float* Wo   = (const float*)d_in[9];
    float* out = (float*)d_out;

    // Workspace regions (first 100.6MB = old xz footprint, split):
    ushort_t* xzh = (ushort_t*)d_ws;                      // [MROWS, 2*DI] bf16 in-proj out
    float* sbuf  = (float*)d_ws + (size_t)MROWS * 1536;   // [B*DI, SEQ] fp32 scan output
    float* uT    = (float*)d_ws + (size_t)MROWS * 3072;
    float* dtT   = uT    + (size_t)MROWS * DI;
    float* xdbl  = dtT   + (size_t)MROWS * DI;
    float* bcT   = xdbl  + (size_t)MROWS * XDC;           // bc4 interleaved (x_proj epilogue)
    float* xnext = bcT   + (size_t)BATCH * 128 * SEQ;
    float* hend  = xnext;                                 // [B*DI*NC, DS]
    float* h0buf = xnext + (size_t)BATCH * DI * NC * DS;  // [B*DI*NC, DS]

    // bf16 plane homes (all lifetimes disjoint on the serial stream):
    ushort_t* sh  = (ushort_t*)uT;                        // activation plane (layer input)
    ushort_t* wih = (ushort_t*)(dtT + (size_t)MROWS * DM);// [2*DI, DM]
    ushort_t* uh  = (ushort_t*)dtT;                       // u activation plane
    ushort_t* wxh = (ushort_t*)xnext;                     // [256(pad), DI] (dead before scan)
    ushort_t* woh = (ushort_t*)xdbl;                      // [DM, DI]
    ushort_t* yh  = (ushort_t*)xnext;                     // y activation plane

    for (int i = 0; i < DEPTH; i++) {
        const float* Wi_l   = Wi   + (size_t)i * 2 * DI * DM;
        const float* cw_l   = cw   + (size_t)i * DI * DC;
        const float* cb_l   = cb   + (size_t)i * DI;
        const float* Wx_l   = Wx   + (size_t)i * XDC * DI;
        const float* Wdt_l  = Wdt  + (size_t)i * DI * DTR;
        const float* bdt_l  = bdt  + (size_t)i * DI;
        const float* Alog_l = Alog + (size_t)i * DI * DS;
        const float* Dsk_l  = Dsk  + (size_t)i * DI;
        const float* Wo_l   = Wo   + (size_t)i * DM * DI;

        // 1. input plane: layer 0 quantizes x; layer 1 has sh from layer 0's
        //    out-GEMM (mode 1).
        if (i == 0)
            quant_bf16<<<(size_t)MROWS * DM / 1024, 256, 0, stream>>>(x, sh);
        quant_bf16<<<(size_t)2 * DI * DM / 1024, 256, 0, stream>>>(Wi_l, wih);
        // 2. xzh = src @ Wi^T  (bf16 plane output — halves xz traffic)
        gemm_mfma<<<dim3(2 * DI / 128, MROWS / 128), 256, 0, stream>>>(
            sh, wih, nullptr, 2 * DI, DM, DM, DM, xzh, nullptr, 1);
        // 3. u = silu(conv(xzh[:, :DI]))
        conv_silu_T2<<<dim3(DI / 64, SEQ / 64, BATCH), 256, 0, stream>>>(
            xzh, cw_l, cb_l, uT, uh);
        // 4. Wx plane (xnext region; pad rows 176..255 arbitrary garbage —
        //    their MFMA columns are >= 176 and never stored)
        quant_bf16<<<(size_t)XDC * DI / 1024, 256, 0, stream>>>(Wx_l, wxh);
        // 5. xdbl = u @ Wx^T ; B/C columns emitted directly as bc4 (fused
        //    trans_bc), dt-rank columns as fp32 rows into xdbl
        gemm_mfma<<<dim3((XDC + 127) / 128, MROWS / 128), 256, 0, stream>>>(
            uh, wxh, xdbl, XDC, DI, DI, DI, nullptr, (float4*)bcT, 2);
        // 6. dtT = softplus(Wdt @ xdbl_dt^T + bdt)
        gemm_dt_T<<<dim3(SEQ / 128, DI / 128, BATCH), 256, 0, stream>>>(
            Wdt_l, xdbl, bdt_l, dtT);
        // 7. channel-paired truncated-backward chunk-end states
        scan_tail<<<(BATCH * DI * NC) / 8, 256, 0, stream>>>(
            dtT, uT, (const float4*)bcT, Alog_l, hend);
        // 8. cross-chunk combine
        scan_phase2<<<(BATCH * DI) / 4, 256, 0, stream>>>(
            dtT, Alog_l, hend, h0buf);
        // 9. packed channel-pair full scan -> sbuf
        scan_phase3<<<(BATCH * DI * NC) / 8, 256, 0, stream>>>(
            dtT, uT, (const float4*)bcT, Alog_l, h0buf, sbuf);
        // 10. fused gate + quantize -> yh
        gate_split_T<<<dim3(DI / 64, SEQ / 64, BATCH), 256, 0, stream>>>(
            xzh, sbuf, uT, Dsk_l, yh);
        // 11. Wo plane
        quant_bf16<<<(size_t)DM * DI / 1024, 256, 0, stream>>>(Wo_l, woh);
        // 12. out = y @ Wo^T ; layer 0 emits next-layer activation plane sh
        if (i == DEPTH - 1)
            gemm_mfma<<<dim3(DM / 128, MROWS / 128), 256, 0, stream>>>(
                yh, woh, out, DM, DI, DI, DI, nullptr, nullptr, 0);
        else
            gemm_mfma<<<dim3(DM / 128, MROWS / 128), 256, 0, stream>>>(
                yh, woh, nullptr, DM, DI, DI, DI, sh, nullptr, 1);
    }
}

// Round 12
// 1094.390 us; speedup vs baseline: 1.1335x; 1.1335x over previous
//
#include <hip/hip_runtime.h>
#include <hip/hip_bf16.h>
#include <math.h>

// Problem constants (MambaStack reference)
#define DEPTH   2
#define DM      768      // d_model
#define DS      64       // d_state
#define DC      4        // d_conv
#define DI      1536     // d_inner
#define DTR     48       // dt_rank
#define BATCH   4
#define SEQ     2048
#define MROWS   (BATCH*SEQ)          // 8192
#define XDC     (DTR + 2*DS)         // 176 (xdbl cols)
#define NC      8                    // scan chunks
#define TCH     (SEQ/NC)             // 256 timesteps per chunk
#define LOG2E   1.44269504088896f

typedef __attribute__((ext_vector_type(8))) short bf16x8;
typedef __attribute__((ext_vector_type(4))) float f32x4;
typedef __attribute__((ext_vector_type(2))) float f32x2;
typedef __attribute__((ext_vector_type(2))) unsigned int uint2v;
typedef unsigned short ushort_t;
#define GAS __attribute__((address_space(1)))
#define LAS __attribute__((address_space(3)))

__device__ __forceinline__ float silu_fast(float x) {
    return x / (1.f + __expf(-x));
}
__device__ __forceinline__ float softplus_acc(float x) {
    return x > 20.f ? x : log1pf(expf(x));
}

// RNE fp32 -> bf16.
__device__ __forceinline__ ushort_t bf16_hi(float f) {
    unsigned u = __float_as_uint(f);
    unsigned hr = u + 0x7FFF + ((u >> 16) & 1);
    return (ushort_t)(hr >> 16);
}

// ---------- VALU-pipe cross-lane reduction helpers (float2, no LDS) ----------
__device__ __forceinline__ f32x2 merge_x32_2(f32x2 a, f32x2 b) {
#if __has_builtin(__builtin_amdgcn_permlane32_swap)
    const uint2v rx = __builtin_amdgcn_permlane32_swap(
        __float_as_uint(a.x), __float_as_uint(b.x), false, false);
    const uint2v ry = __builtin_amdgcn_permlane32_swap(
        __float_as_uint(a.y), __float_as_uint(b.y), false, false);
    const f32x2 s0 = {__uint_as_float(rx[0]), __uint_as_float(ry[0])};
    const f32x2 s1 = {__uint_as_float(rx[1]), __uint_as_float(ry[1])};
    return s0 + s1;
#else
    const f32x2 sa = {a.x + __shfl_xor(a.x, 32, 64), a.y + __shfl_xor(a.y, 32, 64)};
    const f32x2 sb = {b.x + __shfl_xor(b.x, 32, 64), b.y + __shfl_xor(b.y, 32, 64)};
    return (threadIdx.x & 32) ? sb : sa;
#endif
}

__device__ __forceinline__ f32x2 merge_x16_2(f32x2 a, f32x2 b) {
#if __has_builtin(__builtin_amdgcn_permlane16_swap)
    const uint2v rx = __builtin_amdgcn_permlane16_swap(
        __float_as_uint(a.x), __float_as_uint(b.x), false, false);
    const uint2v ry = __builtin_amdgcn_permlane16_swap(
        __float_as_uint(a.y), __float_as_uint(b.y), false, false);
    const f32x2 s0 = {__uint_as_float(rx[0]), __uint_as_float(ry[0])};
    const f32x2 s1 = {__uint_as_float(rx[1]), __uint_as_float(ry[1])};
    return s0 + s1;
#else
    const f32x2 sa = {a.x + __shfl_xor(a.x, 16, 64), a.y + __shfl_xor(a.y, 16, 64)};
    const f32x2 sb = {b.x + __shfl_xor(b.x, 16, 64), b.y + __shfl_xor(b.y, 16, 64)};
    return (threadIdx.x & 16) ? sb : sa;
#endif
}

template <int CTRL>
__device__ __forceinline__ f32x2 dpp_add2(f32x2 x) {
    const int tx = __builtin_amdgcn_update_dpp(
        0, __float_as_int(x.x), CTRL, 0xF, 0xF, true);
    const int ty = __builtin_amdgcn_update_dpp(
        0, __float_as_int(x.y), CTRL, 0xF, 0xF, true);
    const f32x2 t = {__int_as_float(tx), __int_as_float(ty)};
    return x + t;
}
__device__ __forceinline__ f32x2 rowsum16_2(f32x2 x) {
    x = dpp_add2<0x128>(x);   // row_ror:8
    x = dpp_add2<0x124>(x);   // row_ror:4
    x = dpp_add2<0x122>(x);   // row_ror:2
    x = dpp_add2<0x121>(x);   // row_ror:1
    return x;
}

// Contiguous fp32 array -> single bf16 plane.  n multiple of 1024.
__global__ __launch_bounds__(256) void quant_bf16(
    const float* __restrict__ in, ushort_t* __restrict__ hi)
{
    const size_t i = ((size_t)blockIdx.x * 256 + threadIdx.x) * 4;
    const float4 v = *(const float4*)(in + i);
    ushort4 h;
    h.x = bf16_hi(v.x); h.y = bf16_hi(v.y);
    h.z = bf16_hi(v.z); h.w = bf16_hi(v.w);
    *(ushort4*)(hi + i) = h;
}

// ---------------- single-plane bf16 MFMA GEMM ----------------
// C[M,N] = A @ W^T, both single bf16 planes.
// 128x128 tile, BK=32, 4 waves, 1 MFMA per fragment, 2 LDS buffers,
// 16 staging loads per K-step (wave w stages ldid = 4w..4w+3).
// mode 0: fp32 C[row*N+col], col<N guard.
// mode 1: bf16 plane into Chi (row stride N)  [layer-0 out -> next in]
// mode 2: x_proj fused: cols [DTR,DTR+128) -> lane-interleaved bc4 quads,
//         cols <DTR -> fp32 C (stride N), cols >=176 dropped.
// XCD-aware bijective block remap (gridDim.y % 8 == 0 at all call sites).
__global__ __launch_bounds__(256, 2) void gemm_mfma(
    const ushort_t* __restrict__ A, const ushort_t* __restrict__ W,
    float* __restrict__ C, int N, int K, int ldA, int ldW,
    ushort_t* __restrict__ Chi, float4* __restrict__ bc4out, int mode)
{
    __shared__ ushort_t lds[2][128 * 32];
    const int tid  = threadIdx.x;
    const int wave = tid >> 6, lane = tid & 63;

    int bx = blockIdx.x, by = blockIdx.y;
    {   // T1 bijective XCD swizzle
        const int X   = gridDim.x;
        const int fid = by * X + bx;
        const int xcd = fid & 7;
        const int j   = fid >> 3;
        const int jX  = j / X;
        by = xcd * (gridDim.y >> 3) + jX;
        bx = j - jX * X;
    }
    const int bm0 = by * 128, bn0 = bx * 128;
    const int wm = (wave >> 1) * 64, wn = (wave & 1) * 64;

    const int srow = lane >> 2;           // 0..15
    const int skq  = (lane & 3) * 8;      // k offset in elements

    f32x4 acc[4][4];
#pragma unroll
    for (int i = 0; i < 4; i++)
#pragma unroll
        for (int j = 0; j < 4; j++) acc[i][j] = (f32x4){0.f, 0.f, 0.f, 0.f};

    const int lm  = lane & 15;
    const int kg8 = (lane >> 4) * 8;

    for (int k0 = 0; k0 < K; k0 += 32) {
#pragma unroll
        for (int j = 0; j < 4; j++) {
            const int ldid = wave * 4 + j;          // 0..15
            const int buf  = ldid >> 3;             // 0:A 1:W
            const int slot = ldid & 7;
            const ushort_t* gsrc = buf ? W : A;
            const int ldg = buf ? ldW : ldA;
            const int rb  = buf ? bn0 : bm0;
            const ushort_t* ga = gsrc + (size_t)(rb + slot * 16 + srow) * ldg + k0 + skq;
            __builtin_amdgcn_global_load_lds(
                (const GAS unsigned*)ga, (LAS unsigned*)&lds[buf][slot * 512], 16, 0, 0);
        }
        __syncthreads();

        bf16x8 ah[4], bh[4];
#pragma unroll
        for (int i = 0; i < 4; i++) {
            const int ar = (wm + i * 16 + lm) * 32 + kg8;
            ah[i] = *(const bf16x8*)&lds[0][ar];
            const int br = (wn + i * 16 + lm) * 32 + kg8;
            bh[i] = *(const bf16x8*)&lds[1][br];
        }
#pragma unroll
        for (int mi = 0; mi < 4; mi++)
#pragma unroll
            for (int ni = 0; ni < 4; ni++)
                acc[mi][ni] = __builtin_amdgcn_mfma_f32_16x16x32_bf16(
                    ah[mi], bh[ni], acc[mi][ni], 0, 0, 0);
        __syncthreads();
    }

#pragma unroll
    for (int mi = 0; mi < 4; mi++)
#pragma unroll
        for (int ni = 0; ni < 4; ni++) {
            const int rowb = bm0 + wm + mi * 16 + (lane >> 4) * 4;  // mult of 4
            const int colg = bn0 + wn + ni * 16 + lm;
            if (mode == 1) {
#pragma unroll
                for (int r = 0; r < 4; r++)
                    Chi[(size_t)(rowb + r) * N + colg] = bf16_hi(acc[mi][ni][r]);
            } else if (mode == 2) {
                if (colg >= DTR && colg < DTR + 2 * DS) {
                    const f32x4 a = acc[mi][ni];
                    bc4out[(size_t)(rowb >> 2) * 128 + (colg - DTR)] =
                        make_float4(a[0], a[1], a[2], a[3]);
                } else if (colg < DTR) {
#pragma unroll
                    for (int r = 0; r < 4; r++)
                        C[(size_t)(rowb + r) * N + colg] = acc[mi][ni][r];
                }
            } else {
#pragma unroll
                for (int r = 0; r < 4; r++)
                    if (colg < N)
                        C[(size_t)(rowb + r) * N + colg] = acc[mi][ni][r];
            }
        }
}

// dt GEMM, transposed output: dtT[(b*DI+d)*SEQ + t] =
//   softplus(sum_k Wdt[d][k] * xdbl[b*SEQ+t][k] + bias[d]).
__global__ __launch_bounds__(256, 2) void gemm_dt_T(
    const float* __restrict__ Wdt, const float* __restrict__ xdbl,
    const float* __restrict__ bias, float* __restrict__ dtT)
{
    __shared__ float As[8][132];
    __shared__ float Bs[8][132];
    const int tid = threadIdx.x;
    const int bd0 = blockIdx.y * 128;   // d tile
    const int bt0 = blockIdx.x * 128;   // t tile
    const int b   = blockIdx.z;
    const int tx = tid & 15;            // t group
    const int ty = tid >> 4;            // d group
    const int lrow = tid >> 1;
    const int lk4  = (tid & 1) * 4;

    float acc[8][8];
#pragma unroll
    for (int i = 0; i < 8; i++)
#pragma unroll
        for (int j = 0; j < 8; j++) acc[i][j] = 0.f;

    for (int k0 = 0; k0 < DTR; k0 += 8) {
        const float4 av = *(const float4*)(Wdt + (size_t)(bd0 + lrow) * DTR + k0 + lk4);
        const float4 wv = *(const float4*)(xdbl + ((size_t)b * SEQ + bt0 + lrow) * XDC + k0 + lk4);
        __syncthreads();
        As[lk4 + 0][lrow] = av.x; As[lk4 + 1][lrow] = av.y;
        As[lk4 + 2][lrow] = av.z; As[lk4 + 3][lrow] = av.w;
        Bs[lk4 + 0][lrow] = wv.x; Bs[lk4 + 1][lrow] = wv.y;
        Bs[lk4 + 2][lrow] = wv.z; Bs[lk4 + 3][lrow] = wv.w;
        __syncthreads();
#pragma unroll
        for (int kk = 0; kk < 8; kk++) {
            const float4 a0 = *(const float4*)&As[kk][ty * 8];
            const float4 a1 = *(const float4*)&As[kk][ty * 8 + 4];
            const float4 b0 = *(const float4*)&Bs[kk][tx * 8];
            const float4 b1 = *(const float4*)&Bs[kk][tx * 8 + 4];
            const float ar[8] = {a0.x, a0.y, a0.z, a0.w, a1.x, a1.y, a1.z, a1.w};
            const float br[8] = {b0.x, b0.y, b0.z, b0.w, b1.x, b1.y, b1.z, b1.w};
#pragma unroll
            for (int i = 0; i < 8; i++)
#pragma unroll
                for (int j = 0; j < 8; j++)
                    acc[i][j] = fmaf(ar[i], br[j], acc[i][j]);
        }
    }

#pragma unroll
    for (int i = 0; i < 8; i++) {
        const int d = bd0 + ty * 8 + i;
        const float bb = bias[d];
#pragma unroll
        for (int j4 = 0; j4 < 8; j4 += 4) {
            float4 v = make_float4(acc[i][j4], acc[i][j4 + 1], acc[i][j4 + 2], acc[i][j4 + 3]);
            v.x = softplus_acc(v.x + bb);
            v.y = softplus_acc(v.y + bb);
            v.z = softplus_acc(v.z + bb);
            v.w = softplus_acc(v.w + bb);
            *(float4*)(dtT + ((size_t)b * DI + d) * SEQ + bt0 + tx * 8 + j4) = v;
        }
    }
}

// Depthwise causal conv (K=4) + SiLU -> uT [b][d][t] fp32 AND row-major
// bf16 plane (activation operand of the x_proj GEMM).
__global__ __launch_bounds__(256) void conv_silu_T2(
    const float* __restrict__ xz, const float* __restrict__ cw,
    const float* __restrict__ cb, float* __restrict__ uT,
    ushort_t* __restrict__ uh)
{
    __shared__ float tin[67][65];
    __shared__ float ttr[64][65];
    const int tid = threadIdx.x;
    const int d0 = blockIdx.x * 64, t0 = blockIdx.y * 64, b = blockIdx.z;
    const int cl = tid & 63, q = tid >> 6;

    for (int r = q; r < 67; r += 4) {
        const int t = t0 - 3 + r;
        float v = 0.f;
        if (t >= 0) v = xz[((size_t)b * SEQ + t) * (2 * DI) + d0 + cl];
        tin[r][cl] = v;
    }
    __syncthreads();

    const float4 w = ((const float4*)cw)[d0 + cl];
    const float bb = cb[d0 + cl];
#pragma unroll
    for (int i = 0; i < 16; i++) {
        const int t = q * 16 + i;
        float a = bb;
        a = fmaf(tin[t + 0][cl], w.x, a);
        a = fmaf(tin[t + 1][cl], w.y, a);
        a = fmaf(tin[t + 2][cl], w.z, a);
        a = fmaf(tin[t + 3][cl], w.w, a);
        a = silu_fast(a);
        ttr[cl][t] = a;
        const size_t row = (size_t)b * SEQ + t0 + t;
        uh[row * DI + d0 + cl] = bf16_hi(a);   // coalesced in d
    }
    __syncthreads();
#pragma unroll
    for (int i = 0; i < 16; i++) {
        const int d = q * 16 + i;
        uT[((size_t)b * DI + d0 + d) * SEQ + t0 + cl] = ttr[d][cl];  // coalesced in t
    }
}

// ---------------- Chunked selective scan ----------------
// s output lives in the dead xz x-half via the linear map
//   addr(L) = (L/1536)*3072 + L%1536,  L = bd*SEQ + t.

// Channel-paired truncated-backward chunk-end state (f32x2, shared B):
//   hend = sum_t exp2(An * R_t) * dt_t*u_t*B_t,   R_t = suffix-sum of dt.
// Early exit when BOTH channels' remaining weights underflow 2^-30.
#define TAIL_STEP(E, G)                                                \
    {                                                                  \
        const f32x2 dte = {dt0[G].E, dt1[G].E};                        \
        const f32x2 ue  = {u0v[G].E, u1v[G].E};                        \
        const f32x2 w2  = An2 * r2;                                    \
        const f32x2 ee  = {__builtin_amdgcn_exp2f(w2.x),               \
                           __builtin_amdgcn_exp2f(w2.y)};              \
        h2 = h2 + ee * ((dte * ue) * B4[G].E);                         \
        r2 = r2 + dte;                                                 \
    }

__global__ __launch_bounds__(256, 2) void scan_tail(
    const float* __restrict__ dtT, const float* __restrict__ uT,
    const float4* __restrict__ bc4, const float* __restrict__ A_log,
    float* __restrict__ hend)
{
    const int wid  = __builtin_amdgcn_readfirstlane(
                        (int)((blockIdx.x * 256 + threadIdx.x) >> 6));
    const int lane = threadIdx.x & 63;
    const int c   = wid & (NC - 1);
    const int bdq = wid >> 3;
    const int bd0 = bdq * 2;
    const int b   = bd0 / DI;
    const int d0  = bd0 - b * DI;

    const f32x2 An2 = {-expf(A_log[(size_t)d0 * DS + lane]) * LOG2E,
                       -expf(A_log[(size_t)(d0 + 1) * DS + lane]) * LOG2E};
    const float* dtp0 = dtT + (size_t)bd0 * SEQ + c * TCH;
    const float* dtp1 = dtp0 + SEQ;
    const float* up0  = uT  + (size_t)bd0 * SEQ + c * TCH;
    const float* up1  = up0 + SEQ;
    const float4* Bp = bc4 + ((size_t)b * (SEQ / 4) + c * (TCH / 4)) * 128 + lane;

    f32x2 h2 = {0.f, 0.f}, r2 = {0.f, 0.f};
    for (int tb = TCH - 16; tb >= 0; tb -= 16) {
        float4 dt0[4], dt1[4], u0v[4], u1v[4], B4[4];
#pragma unroll
        for (int g = 0; g < 4; g++) {
            dt0[g] = *(const float4*)(dtp0 + tb + 4 * g);
            dt1[g] = *(const float4*)(dtp1 + tb + 4 * g);
            u0v[g] = *(const float4*)(up0 + tb + 4 * g);
            u1v[g] = *(const float4*)(up1 + tb + 4 * g);
            B4[g]  = Bp[(size_t)(tb / 4 + g) * 128];
        }
#pragma unroll
        for (int g = 3; g >= 0; g--) {
            TAIL_STEP(w, g)
            TAIL_STEP(z, g)
            TAIL_STEP(y, g)
            TAIL_STEP(x, g)
        }
        if (__all((An2.x * r2.x < -30.f) && (An2.y * r2.y < -30.f))) break;
    }
    hend[((size_t)bd0 * NC + c) * DS + lane]       = h2.x;
    hend[((size_t)(bd0 + 1) * NC + c) * DS + lane] = h2.y;
}

// Cross-chunk combine (computes per-chunk dt sums internally).
__global__ __launch_bounds__(256) void scan_phase2(
    const float* __restrict__ dtT, const float* __restrict__ A_log,
    const float* __restrict__ hend, float* __restrict__ h0out)
{
    const int bd   = (blockIdx.x * 256 + threadIdx.x) >> 6;
    const int lane = threadIdx.x & 63;
    const int d    = bd % DI;

    const float* dtp = dtT + (size_t)bd * SEQ + lane * 32;
    float s = 0.f;
#pragma unroll
    for (int g = 0; g < 8; g++) {
        const float4 v = *(const float4*)(dtp + 4 * g);
        s += (v.x + v.y) + (v.z + v.w);
    }
    s += __shfl_xor(s, 1, 64);
    s += __shfl_xor(s, 2, 64);
    s += __shfl_xor(s, 4, 64);   // lanes 8c..8c+7 all hold chunk-c sum

    const float An = -expf(A_log[d * DS + lane]) * LOG2E;
    float h = 0.f;
#pragma unroll
    for (int c = 0; c < NC; c++) {
        const float sdt = __shfl(s, 8 * c, 64);
        const size_t off = ((size_t)bd * NC + c) * DS + lane;
        h0out[off] = h;
        h = fmaf(__builtin_amdgcn_exp2f(An * sdt), h, hend[off]);
    }
}

// Channel-paired packed-fp32 full scan.  Wave covers channels (bd0, bd0+1)
// of one chunk; lane = state n for BOTH channels.  B/C are channel-
// independent -> their loads and the whole fold-tree reduce are shared;
// all per-t math is float2 (v_pk_mul/fma_f32), halving issue slots per
// channel.  Reduce/writer mapping is the R8-verified fold tree, lifted
// component-wise to float2.

#define LOAD6(D0, D1, U0, U1, BB_, CC_, TB)                            \
    _Pragma("unroll")                                                  \
    for (int g = 0; g < 4; g++) {                                      \
        D0[g]  = *(const float4*)(dtp0 + (TB) + 4 * g);                \
        D1[g]  = *(const float4*)(dtp1 + (TB) + 4 * g);                \
        U0[g]  = *(const float4*)(up0 + (TB) + 4 * g);                 \
        U1[g]  = *(const float4*)(up1 + (TB) + 4 * g);                 \
        BB_[g] = Bp[(size_t)((TB) / 4 + g) * 128];                     \
        CC_[g] = Cp[(size_t)((TB) / 4 + g) * 128];                     \
    }

#define P3_STEP(E, G, D0, D1, U0, U1, BB_, CC_, LF)                    \
    {                                                                  \
        const f32x2 dte = {D0[G].E, D1[G].E};                          \
        const f32x2 ue  = {U0[G].E, U1[G].E};                          \
        f32x2 w2 = dte * An2;                                          \
        const f32x2 ee = {__builtin_amdgcn_exp2f(w2.x),                \
                          __builtin_amdgcn_exp2f(w2.y)};               \
        const f32x2 p2 = (dte * ue) * BB_[G].E;                        \
        h2 = ee * h2 + p2;                                             \
        LF = h2 * CC_[G].E;                                            \
    }

#define P3_BLOCK(D0, D1, U0, U1, BB_, CC_, TBASE)                      \
    {                                                                  \
        f32x2 m[8];                                                    \
        _Pragma("unroll")                                              \
        for (int g = 0; g < 4; g++) {                                  \
            f32x2 lf0, lf1, lf2, lf3;                                  \
            P3_STEP(x, g, D0, D1, U0, U1, BB_, CC_, lf0)               \
            P3_STEP(y, g, D0, D1, U0, U1, BB_, CC_, lf1)               \
            P3_STEP(z, g, D0, D1, U0, U1, BB_, CC_, lf2)               \
            P3_STEP(w, g, D0, D1, U0, U1, BB_, CC_, lf3)               \
            m[2 * g]     = merge_x32_2(lf0, lf1);                      \
            m[2 * g + 1] = merge_x32_2(lf2, lf3);                      \
        }                                                              \
        const f32x2 q0 = rowsum16_2(merge_x16_2(m[0], m[1]));          \
        const f32x2 q1 = rowsum16_2(merge_x16_2(m[2], m[3]));          \
        const f32x2 q2 = rowsum16_2(merge_x16_2(m[4], m[5]));          \
        const f32x2 q3 = rowsum16_2(merge_x16_2(m[6], m[7]));          \
        const f32x2 v = (lane & 2) ? ((lane & 1) ? q3 : q2)            \
                                   : ((lane & 1) ? q1 : q0);           \
        if ((lane & 15) < 4) {                                         \
            sp0[(TBASE) + wtt] = v.x;                                  \
            sp1[(TBASE) + wtt] = v.y;                                  \
        }                                                              \
    }

__global__ __launch_bounds__(256, 2) void scan_phase3(
    const float* __restrict__ dtT, const float* __restrict__ uT,
    const float4* __restrict__ bc4, const float* __restrict__ A_log,
    const float* __restrict__ hin, float* __restrict__ sX)
{
    const int tid  = threadIdx.x;
    const int wid  = __builtin_amdgcn_readfirstlane(
                        (int)((blockIdx.x * 256 + tid) >> 6));
    const int lane = tid & 63;
    const int c   = wid & (NC - 1);
    const int bdq = wid >> 3;
    const int bd0 = bdq * 2;             // channel pair (bd0, bd0+1), same b
    const int b   = bd0 / DI;
    const int d0  = bd0 - b * DI;

    const f32x2 An2 = {-expf(A_log[(size_t)d0 * DS + lane]) * LOG2E,
                       -expf(A_log[(size_t)(d0 + 1) * DS + lane]) * LOG2E};

    const float* dtp0 = dtT + (size_t)bd0 * SEQ + c * TCH;
    const float* dtp1 = dtp0 + SEQ;
    const float* up0  = uT  + (size_t)bd0 * SEQ + c * TCH;
    const float* up1  = up0 + SEQ;
    const float4* Bp = bc4 + ((size_t)b * (SEQ / 4) + c * (TCH / 4)) * 128 + lane;
    const float4* Cp = Bp + 64;

    const size_t L0 = (size_t)bd0 * SEQ + c * TCH;
    const size_t L1 = L0 + SEQ;
    float* sp0 = sX + (L0 / 1536) * 3072 + (L0 % 1536);
    float* sp1 = sX + (L1 / 1536) * 3072 + (L1 % 1536);

    // writer mapping for the fold-tree reduce: perm[r] = [0,2,1,3]
    const int wr  = lane >> 4;
    const int wtt = 4 * (lane & 3) + (((wr & 1) << 1) | (wr >> 1));

    f32x2 h2 = {hin[((size_t)bd0 * NC + c) * DS + lane],
                hin[((size_t)(bd0 + 1) * NC + c) * DS + lane]};

    float4 dA0[4], dA1[4], uA0[4], uA1[4], BA4[4], CA4[4];
    float4 dB0[4], dB1[4], uB0[4], uB1[4], BB4[4], CB4[4];
    LOAD6(dA0, dA1, uA0, uA1, BA4, CA4, 0);

    for (int tb = 0; tb < TCH; tb += 32) {
        LOAD6(dB0, dB1, uB0, uB1, BB4, CB4, tb + 16);
        P3_BLOCK(dA0, dA1, uA0, uA1, BA4, CA4, tb);
        LOAD6(dA0, dA1, uA0, uA1, BA4, CA4, tb + 32);  // final iter overreads (safe)
        P3_BLOCK(dB0, dB1, uB0, uB1, BB4, CB4, tb + 16);
    }
}

// Fused gate + transpose + bf16 quantize:
//   y = (s + D*u) * silu(z), emitted as a single row-major bf16 plane yh.
__global__ __launch_bounds__(256) void gate_split_T(
    const float* __restrict__ xz, const float* __restrict__ uT,
    const float* __restrict__ Dskip, ushort_t* __restrict__ yh)
{
    __shared__ float zt[64][65];   // [t][d]
    __shared__ float yt[64][65];   // [d][t]
    const int tid = threadIdx.x;
    const int d0 = blockIdx.x * 64, t0 = blockIdx.y * 64, b = blockIdx.z;
    const int cl = tid & 63, q = tid >> 6;
#pragma unroll
    for (int i = 0; i < 16; i++) {
        const int r = q * 16 + i;
        zt[r][cl] = xz[((size_t)b * SEQ + t0 + r) * (2 * DI) + DI + d0 + cl];
    }
    __syncthreads();
#pragma unroll
    for (int i = 0; i < 16; i++) {
        const int dd = q * 16 + i;
        const size_t Lrow = ((size_t)b * DI + d0 + dd) * SEQ + t0;
        const float s = xz[(Lrow / 1536) * 3072 + (Lrow % 1536) + cl];
        const float u = uT[Lrow + cl];
        const float Dd = Dskip[d0 + dd];   // wave-uniform
        yt[dd][cl] = (s + Dd * u) * silu_fast(zt[cl][dd]);
    }
    __syncthreads();
#pragma unroll
    for (int i = 0; i < 16; i++) {
        const int t = q * 16 + i;
        const size_t row = (size_t)b * SEQ + t0 + t;
        yh[row * DI + d0 + cl] = bf16_hi(yt[cl][t]);   // coalesced in d
    }
}

extern "C" void kernel_launch(void* const* d_in, const int* in_sizes, int n_in,
                              void* d_out, int out_size, void* d_ws, size_t ws_size,
                              hipStream_t stream) {
    (void)in_sizes; (void)n_in; (void)out_size; (void)ws_size;
    const float* x    = (const float*)d_in[0];
    const float* Wi   = (const float*)d_in[1];
    const float* cw   = (const float*)d_in[2];
    const float* cb   = (const float*)d_in[3];
    const float* Wx   = (const float*)d_in[4];
    const float* Wdt  = (const float*)d_in[5];
    const float* bdt  = (const float*)d_in[6];
    const float* Alog = (const float*)d_in[7];
    const float* Dsk  = (const float*)d_in[8];
    const float* Wo   = (const float*)d_in[9];
    float* out = (float*)d_out;

    // Workspace (fp32) regions:
    float* xz    = (float*)d_ws;                          // [MROWS, 3072]
    float* uT    = xz    + (size_t)MROWS * (2 * DI);
    float* dtT   = uT    + (size_t)MROWS * DI;
    float* xdbl  = dtT   + (size_t)MROWS * DI;
    float* bcT   = xdbl  + (size_t)MROWS * XDC;           // bc4 interleaved (x_proj epilogue)
    float* xnext = bcT   + (size_t)BATCH * 128 * SEQ;
    float* hend  = xnext;                                 // [B*DI*NC, DS]
    float* h0buf = xnext + (size_t)BATCH * DI * NC * DS;  // [B*DI*NC, DS]

    // bf16 plane homes (all lifetimes disjoint on the serial stream):
    ushort_t* sh  = (ushort_t*)uT;                        // activation plane (layer input)
    ushort_t* wih = (ushort_t*)(dtT + (size_t)MROWS * DM);// [2*DI, DM]
    ushort_t* uh  = (ushort_t*)dtT;                       // u activation plane
    ushort_t* wxh = (ushort_t*)xnext;                     // [256(pad), DI] (dead before scan)
    ushort_t* woh = (ushort_t*)xdbl;                      // [DM, DI]
    ushort_t* yh  = (ushort_t*)xnext;                     // y activation plane

    for (int i = 0; i < DEPTH; i++) {
        const float* Wi_l   = Wi   + (size_t)i * 2 * DI * DM;
        const float* cw_l   = cw   + (size_t)i * DI * DC;
        const float* cb_l   = cb   + (size_t)i * DI;
        const float* Wx_l   = Wx   + (size_t)i * XDC * DI;
        const float* Wdt_l  = Wdt  + (size_t)i * DI * DTR;
        const float* bdt_l  = bdt  + (size_t)i * DI;
        const float* Alog_l = Alog + (size_t)i * DI * DS;
        const float* Dsk_l  = Dsk  + (size_t)i * DI;
        const float* Wo_l   = Wo   + (size_t)i * DM * DI;

        // 1. input plane: layer 0 quantizes x; layer 1 has sh from layer 0's
        //    out-GEMM (mode 1).
        if (i == 0)
            quant_bf16<<<(size_t)MROWS * DM / 1024, 256, 0, stream>>>(x, sh);
        quant_bf16<<<(size_t)2 * DI * DM / 1024, 256, 0, stream>>>(Wi_l, wih);
        // 2. xz = src @ Wi^T
        gemm_mfma<<<dim3(2 * DI / 128, MROWS / 128), 256, 0, stream>>>(
            sh, wih, xz, 2 * DI, DM, DM, DM, nullptr, nullptr, 0);
        // 3. u = silu(conv(xz[:, :DI]))
        conv_silu_T2<<<dim3(DI / 64, SEQ / 64, BATCH), 256, 0, stream>>>(
            xz, cw_l, cb_l, uT, uh);
        // 4. Wx plane (xnext region; pad rows 176..255 arbitrary garbage —
        //    their MFMA columns are >= 176 and never stored)
        quant_bf16<<<(size_t)XDC * DI / 1024, 256, 0, stream>>>(Wx_l, wxh);
        // 5. xdbl = u @ Wx^T ; B/C columns emitted directly as bc4 (fused
        //    trans_bc), dt-rank columns as fp32 rows into xdbl
        gemm_mfma<<<dim3((XDC + 127) / 128, MROWS / 128), 256, 0, stream>>>(
            uh, wxh, xdbl, XDC, DI, DI, DI, nullptr, (float4*)bcT, 2);
        // 6. dtT = softplus(Wdt @ xdbl_dt^T + bdt)
        gemm_dt_T<<<dim3(SEQ / 128, DI / 128, BATCH), 256, 0, stream>>>(
            Wdt_l, xdbl, bdt_l, dtT);
        // 7. channel-paired truncated-backward chunk-end states
        scan_tail<<<(BATCH * DI * NC) / 8, 256, 0, stream>>>(
            dtT, uT, (const float4*)bcT, Alog_l, hend);
        // 8. cross-chunk combine
        scan_phase2<<<(BATCH * DI) / 4, 256, 0, stream>>>(
            dtT, Alog_l, hend, h0buf);
        // 9. packed channel-pair full scan; writes s into xz x-half (mapped)
        scan_phase3<<<(BATCH * DI * NC) / 8, 256, 0, stream>>>(
            dtT, uT, (const float4*)bcT, Alog_l, h0buf, xz);
        // 10. fused gate + quantize -> yh
        gate_split_T<<<dim3(DI / 64, SEQ / 64, BATCH), 256, 0, stream>>>(
            xz, uT, Dsk_l, yh);
        // 11. Wo plane
        quant_bf16<<<(size_t)DM * DI / 1024, 256, 0, stream>>>(Wo_l, woh);
        // 12. out = y @ Wo^T ; layer 0 emits next-layer activation plane sh
        if (i == DEPTH - 1)
            gemm_mfma<<<dim3(DM / 128, MROWS / 128), 256, 0, stream>>>(
                yh, woh, out, DM, DI, DI, DI, nullptr, nullptr, 0);
        else
            gemm_mfma<<<dim3(DM / 128, MROWS / 128), 256, 0, stream>>>(
                yh, woh, nullptr, DM, DI, DI, DI, sh, nullptr, 1);
    }
}